// Round 2
// baseline (262.212 us; speedup 1.0000x reference)
//
#include <hip/hip_runtime.h>
#include <hip/hip_bf16.h>
#include <stdint.h>

// Problem: B=8, L=1024, C=1024, H=16, HD=64, window +/-64 (WS=128).
// Round-11: round-10's 8-phase 256x256 regressed (101us, MfmaUtil 20%):
// compiler drains LDS-DMA before ds_reads -> counted vmcnt defeated, at
// 1 blk/CU with no cross-block overlap. This round: minimal-2-phase counted
// pipeline on the PROVEN r9 128x128 geometry: double-buffered LDS (64KB,
// 2 blk/CU kept), ds_reads FIRST (outstanding DMA=0 -> auto-drain free),
// stage t+1 under the MFMA window, vmcnt(0) AFTER compute, ONE barrier/iter.
// T1 XCD swizzle kept (proven FETCH 77->59.5MB). cast/attn unchanged.

typedef __attribute__((ext_vector_type(8))) short bf16x8;
typedef __attribute__((ext_vector_type(4))) float f32x4;

__device__ inline unsigned short f2b(float f) {
    __hip_bfloat16 h = __float2bfloat16(f);
    return *reinterpret_cast<unsigned short*>(&h);
}

// async global->LDS, 16B per lane; LDS dest = wave-uniform base + lane*16
__device__ inline void gld16(const unsigned short* g, unsigned short* l) {
    __builtin_amdgcn_global_load_lds(
        (const __attribute__((address_space(1))) void*)g,
        (__attribute__((address_space(3))) void*)l, 16, 0, 0);
}

#define BM 128
#define BN 128
#define BK 64

// ---- cast f32 inputs to bf16 side buffers: 8 f32 -> one 16B store ----
__global__ void __launch_bounds__(256) cast_inputs(
    const float4* __restrict__ x, const float4* __restrict__ w1,
    const float4* __restrict__ w2,
    uint4* __restrict__ xb, uint4* __restrict__ w1b, uint4* __restrict__ w2b)
{
    const int P0 = 1048576, P1 = 393216, P2 = 131072;  // float4-pair counts
    int stride = gridDim.x * blockDim.x;
    for (int i = blockIdx.x * blockDim.x + threadIdx.x; i < P0 + P1 + P2; i += stride) {
        const float4* src; uint4* dst; int idx;
        if (i < P0)           { src = x;  dst = xb;  idx = i; }
        else if (i < P0 + P1) { src = w1; dst = w1b; idx = i - P0; }
        else                  { src = w2; dst = w2b; idx = i - P0 - P1; }
        float4 a = src[idx * 2], b = src[idx * 2 + 1];
        unsigned short t[8] = {f2b(a.x), f2b(a.y), f2b(a.z), f2b(a.w),
                               f2b(b.x), f2b(b.y), f2b(b.z), f2b(b.w)};
        dst[idx] = *(uint4*)t;
    }
}

// ================= 2-phase counted-vmcnt 128x128 GEMM =================
// C[M=8192, N] = A[M,1024] * W[N,1024]^T + bias.  4 waves, 256 thr.
// LDS: As/Bs double-buffered (64 KiB total -> 2 blocks/CU).
// Per iter: ds_read frags(buf) ; DMA-stage tile t+1 -> buf^1 ;
//           lgkmcnt(0)+sched_barrier ; 32 MFMA ; vmcnt(0) ; s_barrier.
// ds_reads run with zero outstanding DMA (prior iter drained), so any
// compiler-inserted LDS-DMA alias wait is free; the only vmcnt wait is
// AFTER the MFMA window -> residual latency ~= max(0, 900 - 620 - reads).

#define STG(BUF, T) do {                                                      \
    _Pragma("unroll")                                                         \
    for (int p = 0; p < 4; ++p) {                                             \
        gld16(ga[p] + (T) * 64, &As[BUF][(wave * 32 + p * 8) * 64]);          \
        gld16(gb[p] + (T) * 64, &Bs[BUF][(wave * 32 + p * 8) * 64]);          \
    } } while (0)

#define RDS(BUF) do {                                                         \
    _Pragma("unroll")                                                         \
    for (int i = 0; i < 4; ++i) {                                             \
        _Pragma("unroll")                                                     \
        for (int h = 0; h < 2; ++h) {                                         \
            af[i][h]  = *(const bf16x8*)&As[BUF][(mblk + i * 16 + lm) * 64 +  \
                                                 (((h * 4 + quad) ^ lm7) << 3)]; \
            bfr[i][h] = *(const bf16x8*)&Bs[BUF][(nblk + i * 16 + lm) * 64 +  \
                                                 (((h * 4 + quad) ^ lm7) << 3)]; \
        }                                                                     \
    } } while (0)

#define MMA do {                                                              \
    asm volatile("s_waitcnt lgkmcnt(0)" ::: "memory");                        \
    __builtin_amdgcn_sched_barrier(0);                                        \
    _Pragma("unroll")                                                         \
    for (int i = 0; i < 4; ++i) {                                             \
        _Pragma("unroll")                                                     \
        for (int j = 0; j < 4; ++j) {                                         \
            acc[i][j] = __builtin_amdgcn_mfma_f32_16x16x32_bf16(              \
                af[i][0], bfr[j][0], acc[i][j], 0, 0, 0);                     \
            acc[i][j] = __builtin_amdgcn_mfma_f32_16x16x32_bf16(              \
                af[i][1], bfr[j][1], acc[i][j], 0, 0, 0);                     \
        }                                                                     \
    } } while (0)

#define ITER(BUF, T) do {                                                     \
    RDS(BUF);                                                                 \
    STG(1 - (BUF), (T) + 1);                                                  \
    MMA;                                                                      \
    asm volatile("s_waitcnt vmcnt(0)" ::: "memory");                          \
    __builtin_amdgcn_s_barrier();                                             \
} while (0)

template<bool SCATTER>
__global__ void __launch_bounds__(256) gemm2p(
    const unsigned short* __restrict__ A,    // [8192,1024] bf16
    const unsigned short* __restrict__ W,    // [NDIM,1024] bf16
    const float* __restrict__ bias,          // [NDIM] f32
    unsigned short* __restrict__ Qo,
    unsigned short* __restrict__ Ko,
    unsigned short* __restrict__ Vo,
    float* __restrict__ Out,
    int NBX)
{
    const int K = 1024;
    int tid = threadIdx.x;
    int wave = tid >> 6, lane = tid & 63;
    int lm = lane & 15, quad = lane >> 4;
    int mblk = (wave & 1) * 64, nblk = (wave >> 1) * 64;

    // T1: chunked XCD swizzle (bijective: nwg % 8 == 0)
    int nwg = NBX * 64;
    int id  = blockIdx.y * NBX + blockIdx.x;
    int cpx = nwg >> 3;
    int swz = (id & 7) * cpx + (id >> 3);
    int bx = swz % NBX, by = swz / NBX;
    int n0 = bx * BN, m0 = by * BM;

    __shared__ unsigned short As[2][BM * BK];  // 2 x 16 KiB
    __shared__ unsigned short Bs[2][BN * BK];  // 2 x 16 KiB

    int drow = lane >> 3;               // row within an 8-row DMA chunk
    int gcc  = (lane & 7) ^ drow;       // inverse-swizzled logical col-chunk
    const unsigned short* ga[4]; const unsigned short* gb[4];
#pragma unroll
    for (int p = 0; p < 4; ++p) {
        int r = wave * 32 + p * 8 + drow;
        ga[p] = A + (size_t)(m0 + r) * K + gcc * 8;
        gb[p] = W + (size_t)(n0 + r) * K + gcc * 8;
    }
    int lm7 = lm & 7;

    f32x4 acc[4][4];
#pragma unroll
    for (int i = 0; i < 4; ++i)
#pragma unroll
        for (int j = 0; j < 4; ++j)
            acc[i][j] = (f32x4){0.f, 0.f, 0.f, 0.f};
    bf16x8 af[4][2], bfr[4][2];

    // prologue: stage tile 0 into buf0, drain, sync
    STG(0, 0);
    asm volatile("s_waitcnt vmcnt(0)" ::: "memory");
    __builtin_amdgcn_s_barrier();

#pragma unroll 1
    for (int tp = 0; tp < 7; ++tp) {
        ITER(0, 2 * tp);
        ITER(1, 2 * tp + 1);
    }
    ITER(0, 14);          // stages t=15 -> buf1
    RDS(1);               // t=15, no further staging
    MMA;

    if constexpr (SCATTER) {
#pragma unroll
        for (int j = 0; j < 4; ++j) {
            int n = n0 + nblk + j * 16 + lm;
            float bv = bias[n];
            int sec = n >> 10, rem = n & 1023;
            int h = rem >> 6, d = rem & 63;
            unsigned short* dst = (sec == 0) ? Qo : (sec == 1) ? Ko : Vo;
#pragma unroll
            for (int i = 0; i < 4; ++i) {
#pragma unroll
                for (int r = 0; r < 4; ++r) {
                    int m = m0 + mblk + i * 16 + quad * 4 + r;
                    int bb = m >> 10, sl = m & 1023;
                    size_t idx = ((size_t)((bb * 16 + h) * 1024 + sl)) * 64 + d;
                    dst[idx] = f2b(acc[i][j][r] + bv);
                }
            }
        }
    } else {
#pragma unroll
        for (int j = 0; j < 4; ++j) {
            int n = n0 + nblk + j * 16 + lm;
            float bv = bias[n];
#pragma unroll
            for (int i = 0; i < 4; ++i) {
#pragma unroll
                for (int r = 0; r < 4; ++r) {
                    int m = m0 + mblk + i * 16 + quad * 4 + r;
                    Out[(size_t)m * 1024 + n] = acc[i][j][r] + bv;
                }
            }
        }
    }
}

// ---- local attention (unchanged, proven) ----
__global__ void __launch_bounds__(256) attn_local(
    const unsigned short* __restrict__ Qg,   // [B*H,1024,64] bf16
    const unsigned short* __restrict__ Kg,
    const unsigned short* __restrict__ Vg,
    unsigned short* __restrict__ Og)         // [8192,1024] bf16
{
    const int KP = 72;    // K-tile pitch (64+8)
    const int VP = 200;   // Vt / P pitch (192+8)
    __shared__ unsigned short Ks[192 * KP];  // reused as P after barrier
    __shared__ unsigned short Vt[64 * VP];

    int tid = threadIdx.x;
    int wave = tid >> 6, lane = tid & 63;
    int lm = lane & 15, quad = lane >> 4;

    int bh = blockIdx.x >> 4;
    int qt = blockIdx.x & 15;
    int q0 = qt * 64;
    int b = bh >> 4, h = bh & 15;
    const unsigned short* Qbh = Qg + (size_t)bh * 1024 * 64;
    const unsigned short* Kbh = Kg + (size_t)bh * 1024 * 64;
    const unsigned short* Vbh = Vg + (size_t)bh * 1024 * 64;
    int j0 = q0 - 64;

#pragma unroll
    for (int it = 0; it < 6; ++it) {
        int id = it * 256 + tid;
        int r = id >> 3;
        int c = (id & 7) * 8;
        int j = j0 + r;
        uint4 kv, vv;
        kv.x = kv.y = kv.z = kv.w = 0;
        vv = kv;
        if (j >= 0 && j < 1024) {
            kv = *(const uint4*)(Kbh + (size_t)j * 64 + c);
            vv = *(const uint4*)(Vbh + (size_t)j * 64 + c);
        }
        *(uint4*)(Ks + r * KP + c) = kv;
        unsigned short tmp[8];
        *(uint4*)tmp = vv;
#pragma unroll
        for (int e = 0; e < 8; ++e) Vt[(c + e) * VP + r] = tmp[e];
    }
    __syncthreads();

    int qrow = q0 + wave * 16;
    bf16x8 qf0 = *(const bf16x8*)(Qbh + (size_t)(qrow + lm) * 64 + quad * 8);
    bf16x8 qf1 = *(const bf16x8*)(Qbh + (size_t)(qrow + lm) * 64 + 32 + quad * 8);

    f32x4 sc[9];
#pragma unroll
    for (int kt = 0; kt < 9; ++kt) {
        int akt = wave + kt;
        f32x4 a = (f32x4){0.f, 0.f, 0.f, 0.f};
        bf16x8 k0f = *(const bf16x8*)(Ks + (akt * 16 + lm) * KP + quad * 8);
        bf16x8 k1f = *(const bf16x8*)(Ks + (akt * 16 + lm) * KP + 32 + quad * 8);
        a = __builtin_amdgcn_mfma_f32_16x16x32_bf16(qf0, k0f, a, 0, 0, 0);
        a = __builtin_amdgcn_mfma_f32_16x16x32_bf16(qf1, k1f, a, 0, 0, 0);
        sc[kt] = a;
    }

    float mx[4] = {-3e38f, -3e38f, -3e38f, -3e38f};
#pragma unroll
    for (int kt = 0; kt < 9; ++kt) {
        int jg = j0 + (wave + kt) * 16 + lm;
#pragma unroll
        for (int r = 0; r < 4; ++r) {
            int irow = q0 + wave * 16 + quad * 4 + r;
            int diff = irow - jg;
            bool ok = (jg >= 0) && (jg < 1024) && (diff <= 64) && (diff >= -64);
            float s = ok ? sc[kt][r] * 0.125f : -30000.0f;
            sc[kt][r] = s;
            mx[r] = fmaxf(mx[r], s);
        }
    }
#pragma unroll
    for (int off = 1; off <= 8; off <<= 1)
#pragma unroll
        for (int r = 0; r < 4; ++r)
            mx[r] = fmaxf(mx[r], __shfl_xor(mx[r], off, 64));

    float sum[4] = {0.f, 0.f, 0.f, 0.f};
#pragma unroll
    for (int kt = 0; kt < 9; ++kt)
#pragma unroll
        for (int r = 0; r < 4; ++r) {
            float p = __expf(sc[kt][r] - mx[r]);
            sc[kt][r] = p;
            sum[r] += p;
        }
#pragma unroll
    for (int off = 1; off <= 8; off <<= 1)
#pragma unroll
        for (int r = 0; r < 4; ++r)
            sum[r] += __shfl_xor(sum[r], off, 64);

    __syncthreads();
    unsigned short* Pb = Ks + wave * 3200;  // per-wave P [16][VP]
#pragma unroll
    for (int kt = 0; kt < 9; ++kt) {
        int akt = wave + kt;
#pragma unroll
        for (int r = 0; r < 4; ++r)
            Pb[(quad * 4 + r) * VP + akt * 16 + lm] = f2b(sc[kt][r]);
    }
    {
        int zkt = (wave & 1) ? (wave - 1) : (wave + 9);
#pragma unroll
        for (int r = 0; r < 4; ++r)
            Pb[(quad * 4 + r) * VP + zkt * 16 + lm] = 0;
    }
    __syncthreads();

    int jclo = wave >> 1;
    f32x4 o[4];
#pragma unroll
    for (int n = 0; n < 4; ++n) o[n] = (f32x4){0.f, 0.f, 0.f, 0.f};
#pragma unroll
    for (int jc2 = 0; jc2 < 5; ++jc2) {
        int jc = jclo + jc2;
        bf16x8 pf = *(const bf16x8*)(Pb + lm * VP + jc * 32 + quad * 8);
#pragma unroll
        for (int n = 0; n < 4; ++n) {
            bf16x8 vf = *(const bf16x8*)(Vt + (n * 16 + lm) * VP + jc * 32 + quad * 8);
            o[n] = __builtin_amdgcn_mfma_f32_16x16x32_bf16(pf, vf, o[n], 0, 0, 0);
        }
    }

    float inv[4];
#pragma unroll
    for (int r = 0; r < 4; ++r) inv[r] = 1.0f / sum[r];
#pragma unroll
    for (int n = 0; n < 4; ++n)
#pragma unroll
        for (int r = 0; r < 4; ++r) {
            int orow = q0 + wave * 16 + quad * 4 + r;
            size_t oidx = ((size_t)(b * 1024 + orow)) * 1024 + h * 64 + n * 16 + lm;
            Og[oidx] = f2b(o[n][r] * inv[r]);
        }
}

extern "C" void kernel_launch(void* const* d_in, const int* in_sizes, int n_in,
                              void* d_out, int out_size, void* d_ws, size_t ws_size,
                              hipStream_t stream) {
    const float* x  = (const float*)d_in[0];  // [8,1024,1024] f32
    const float* w1 = (const float*)d_in[1];  // [3072,1024] f32
    const float* b1 = (const float*)d_in[2];  // [3072] f32
    const float* w2 = (const float*)d_in[3];  // [1024,1024] f32
    const float* b2 = (const float*)d_in[4];  // [1024] f32
    float* out = (float*)d_out;               // [8192,1024] f32

    // ws (56 MiB peak):
    //  [0,16Mi)   xb  -> overlaid by attn after gemm_qkv
    //  [16,22Mi)  w1b -> dead after gemm_qkv
    //  [22,24Mi)  w2b
    //  [24,40Mi)  q   [40,56Mi) k
    //  v lives in d_out's first 16 MiB (dead before gemm_proj writes out)
    char* ws = (char*)d_ws;
    const size_t MB = 1024 * 1024;
    unsigned short* xb   = (unsigned short*)(ws);
    unsigned short* w1b  = (unsigned short*)(ws + 16 * MB);
    unsigned short* w2b  = (unsigned short*)(ws + 22 * MB);
    unsigned short* q    = (unsigned short*)(ws + 24 * MB);
    unsigned short* k    = (unsigned short*)(ws + 40 * MB);
    unsigned short* v    = (unsigned short*)d_out;
    unsigned short* attn = (unsigned short*)(ws);

    cast_inputs<<<1536, dim3(256), 0, stream>>>(
        (const float4*)x, (const float4*)w1, (const float4*)w2,
        (uint4*)xb, (uint4*)w1b, (uint4*)w2b);
    gemm2p<true><<<dim3(24, 64), dim3(256), 0, stream>>>(
        xb, w1b, b1, q, k, v, nullptr, 24);
    attn_local<<<dim3(2048), dim3(256), 0, stream>>>(q, k, v, attn);
    gemm2p<false><<<dim3(8, 64), dim3(256), 0, stream>>>(
        attn, w2b, b2, nullptr, nullptr, nullptr, out, 8);
}

// Round 3
// 213.798 us; speedup vs baseline: 1.2264x; 1.2264x over previous
//
#include <hip/hip_runtime.h>
#include <hip/hip_bf16.h>
#include <stdint.h>

// Problem: B=8, L=1024, C=1024, H=16, HD=64, window +/-64 (WS=128).
// Round-12: recovery + one targeted experiment.
//  - GEMMs: restored VERBATIM to the proven round-9 structure (67.5us qkv,
//    763 TF, 5 blk/CU TLP). Rounds 10/11 proved intra-block pipelining loses
//    to cross-block overlap at K=1024, and 128-tile chunked XCD swizzle
//    thrashes L2 (FETCH 77->160MB). Both reverted.
//  - attn: LDS write-conflict fix. V-transpose writes Vt[(c+e)*VP+r] have
//    bank = ((c+e)*100 + r/2) mod 32 with c*100 === 0 mod 32 -> all 8
//    column-groups alias -> 16-way conflict x48 writes. Stagger element
//    order by (tid&7) -> 2-way (free). P-store quad-pairs alias (4-way);
//    permute row order by quad -> <=2-way. Pure write reordering: same
//    data, same layout, same read patterns.

typedef __attribute__((ext_vector_type(8))) short bf16x8;
typedef __attribute__((ext_vector_type(4))) float f32x4;

__device__ inline unsigned short f2b(float f) {
    __hip_bfloat16 h = __float2bfloat16(f);
    return *reinterpret_cast<unsigned short*>(&h);
}

// async global->LDS, 16B per lane; LDS dest = wave-uniform base + lane*16
__device__ inline void gld16(const unsigned short* g, unsigned short* l) {
    __builtin_amdgcn_global_load_lds(
        (const __attribute__((address_space(1))) void*)g,
        (__attribute__((address_space(3))) void*)l, 16, 0, 0);
}

#define BM 128
#define BN 128
#define BK 64

// ---- cast f32 inputs to bf16 side buffers: 8 f32 -> one 16B store ----
__global__ void __launch_bounds__(256) cast_inputs(
    const float4* __restrict__ x, const float4* __restrict__ w1,
    const float4* __restrict__ w2,
    uint4* __restrict__ xb, uint4* __restrict__ w1b, uint4* __restrict__ w2b)
{
    const int P0 = 1048576, P1 = 393216, P2 = 131072;  // float4-pair counts
    int stride = gridDim.x * blockDim.x;
    for (int i = blockIdx.x * blockDim.x + threadIdx.x; i < P0 + P1 + P2; i += stride) {
        const float4* src; uint4* dst; int idx;
        if (i < P0)           { src = x;  dst = xb;  idx = i; }
        else if (i < P0 + P1) { src = w1; dst = w1b; idx = i - P0; }
        else                  { src = w2; dst = w2b; idx = i - P0 - P1; }
        float4 a = src[idx * 2], b = src[idx * 2 + 1];
        unsigned short t[8] = {f2b(a.x), f2b(a.y), f2b(a.z), f2b(a.w),
                               f2b(b.x), f2b(b.y), f2b(b.z), f2b(b.w)};
        dst[idx] = *(uint4*)t;
    }
}

// ---- QKV GEMM: C[M,N] = xb[M,K] * w1b[N,K]^T + b1 ; scatter to Q/K/V ----
// 128x64 LDS tiles, XOR swizzle (chunk c of row r at c^(r&7)); DMA staging.
__global__ void __launch_bounds__(256) gemm_qkv(
    const unsigned short* __restrict__ A,   // xb [8192,1024] bf16
    const unsigned short* __restrict__ W,   // w1b [3072,1024] bf16
    const float* __restrict__ bias,         // [3072] f32
    unsigned short* __restrict__ Qo,
    unsigned short* __restrict__ Ko,
    unsigned short* __restrict__ Vo)
{
    const int K = 1024;
    int n0 = blockIdx.x * BN;
    int m0 = blockIdx.y * BM;
    int tid = threadIdx.x;
    int wave = tid >> 6, lane = tid & 63;
    int lm = lane & 15, quad = lane >> 4;
    int mblk = (wave & 1) * 64, nblk = (wave >> 1) * 64;

    __shared__ unsigned short As[BM * BK];  // 16 KiB
    __shared__ unsigned short Bs[BN * BK];  // 16 KiB

    int drow = lane >> 3;               // 0..7 row within an 8-row DMA chunk
    int gcc  = (lane & 7) ^ drow;       // swizzled logical col-chunk (x8 elems)
    const unsigned short* ga[4]; const unsigned short* gb[4];
    unsigned short *la[4], *lb[4];
#pragma unroll
    for (int p = 0; p < 4; ++p) {
        int r = wave * 32 + p * 8 + drow;
        ga[p] = A + (size_t)(m0 + r) * K + gcc * 8;
        gb[p] = W + (size_t)(n0 + r) * K + gcc * 8;
        la[p] = As + (wave * 32 + p * 8) * 64;
        lb[p] = Bs + (wave * 32 + p * 8) * 64;
    }
    int lm7 = lm & 7;

    f32x4 acc[4][4];
#pragma unroll
    for (int i = 0; i < 4; ++i)
#pragma unroll
        for (int j = 0; j < 4; ++j)
            acc[i][j] = (f32x4){0.f, 0.f, 0.f, 0.f};

    for (int k0 = 0; k0 < K; k0 += BK) {
        __syncthreads();                 // prev iter's ds_reads done
#pragma unroll
        for (int p = 0; p < 4; ++p) gld16(ga[p] + k0, la[p]);
#pragma unroll
        for (int p = 0; p < 4; ++p) gld16(gb[p] + k0, lb[p]);
        __syncthreads();                 // DMA drained
        bf16x8 af[4][2], bfr[4][2];
#pragma unroll
        for (int i = 0; i < 4; ++i)
#pragma unroll
            for (int hhh = 0; hhh < 2; ++hhh)
                af[i][hhh] = *(const bf16x8*)(As + (mblk + i * 16 + lm) * 64 +
                                              (((hhh * 4 + quad) ^ lm7) << 3));
#pragma unroll
        for (int j = 0; j < 4; ++j)
#pragma unroll
            for (int hhh = 0; hhh < 2; ++hhh)
                bfr[j][hhh] = *(const bf16x8*)(Bs + (nblk + j * 16 + lm) * 64 +
                                               (((hhh * 4 + quad) ^ lm7) << 3));
#pragma unroll
        for (int i = 0; i < 4; ++i)
#pragma unroll
            for (int j = 0; j < 4; ++j) {
                acc[i][j] = __builtin_amdgcn_mfma_f32_16x16x32_bf16(af[i][0], bfr[j][0], acc[i][j], 0, 0, 0);
                acc[i][j] = __builtin_amdgcn_mfma_f32_16x16x32_bf16(af[i][1], bfr[j][1], acc[i][j], 0, 0, 0);
            }
    }

#pragma unroll
    for (int j = 0; j < 4; ++j) {
        int n = n0 + nblk + j * 16 + lm;
        float bv = bias[n];
        int sec = n >> 10, rem = n & 1023;
        int h = rem >> 6, d = rem & 63;
        unsigned short* dst = (sec == 0) ? Qo : (sec == 1) ? Ko : Vo;
#pragma unroll
        for (int i = 0; i < 4; ++i) {
#pragma unroll
            for (int r = 0; r < 4; ++r) {
                int m = m0 + mblk + i * 16 + quad * 4 + r;
                int bb = m >> 10, sl = m & 1023;
                size_t idx = ((size_t)((bb * 16 + h) * 1024 + sl)) * 64 + d;
                dst[idx] = f2b(acc[i][j][r] + bv);
            }
        }
    }
}

// ---- local attention ----
// One block per (b,h,64-row q tile). Keys window [q0-64, q0+128) = 192.
// Wave w (q rows [q0+16w,+16)) computes only key tiles [w, w+8] (9 of 12)
// and 5 of 6 PV chunks; the one uncovered tile is zeroed in P.
__global__ void __launch_bounds__(256) attn_local(
    const unsigned short* __restrict__ Qg,   // [B*H,1024,64] bf16
    const unsigned short* __restrict__ Kg,   // [B*H,1024,64] bf16
    const unsigned short* __restrict__ Vg,   // [B*H,1024,64] bf16
    unsigned short* __restrict__ Og)         // [8192,1024] bf16
{
    const int KP = 72;    // K-tile pitch (64+8)
    const int VP = 200;   // Vt / P pitch (192+8)
    __shared__ unsigned short Ks[192 * KP];  // reused as P after barrier
    __shared__ unsigned short Vt[64 * VP];

    int tid = threadIdx.x;
    int wave = tid >> 6, lane = tid & 63;
    int lm = lane & 15, quad = lane >> 4;

    int bh = blockIdx.x >> 4;
    int qt = blockIdx.x & 15;
    int q0 = qt * 64;
    int b = bh >> 4, h = bh & 15;
    const unsigned short* Qbh = Qg + (size_t)bh * 1024 * 64;
    const unsigned short* Kbh = Kg + (size_t)bh * 1024 * 64;
    const unsigned short* Vbh = Vg + (size_t)bh * 1024 * 64;
    int j0 = q0 - 64;

    // stage K rows + V^T. V-transpose writes staggered by (tid&7):
    // bank = (4*((e0+k)&7) + (tid>>3)/2) mod 32 -> 2-way max (was 16-way).
    int k7 = tid & 7;
#pragma unroll
    for (int it = 0; it < 6; ++it) {
        int id = it * 256 + tid;
        int r = id >> 3;             // key row 0..191
        int c = (id & 7) * 8;        // d offset
        int j = j0 + r;
        uint4 kv, vv;
        kv.x = kv.y = kv.z = kv.w = 0;
        vv = kv;
        if (j >= 0 && j < 1024) {
            kv = *(const uint4*)(Kbh + (size_t)j * 64 + c);
            vv = *(const uint4*)(Vbh + (size_t)j * 64 + c);
        }
        *(uint4*)(Ks + r * KP + c) = kv;
        unsigned short tmp[8];
        *(uint4*)tmp = vv;
#pragma unroll
        for (int e0 = 0; e0 < 8; ++e0) {
            int e = (e0 + k7) & 7;
            Vt[(c + e) * VP + r] = tmp[e];
        }
    }
    __syncthreads();

    int qrow = q0 + wave * 16;
    bf16x8 qf0 = *(const bf16x8*)(Qbh + (size_t)(qrow + lm) * 64 + quad * 8);
    bf16x8 qf1 = *(const bf16x8*)(Qbh + (size_t)(qrow + lm) * 64 + 32 + quad * 8);

    // scores: 9 key tiles [wave, wave+8]
    f32x4 sc[9];
#pragma unroll
    for (int kt = 0; kt < 9; ++kt) {
        int akt = wave + kt;
        f32x4 a = (f32x4){0.f, 0.f, 0.f, 0.f};
        bf16x8 k0f = *(const bf16x8*)(Ks + (akt * 16 + lm) * KP + quad * 8);
        bf16x8 k1f = *(const bf16x8*)(Ks + (akt * 16 + lm) * KP + 32 + quad * 8);
        a = __builtin_amdgcn_mfma_f32_16x16x32_bf16(qf0, k0f, a, 0, 0, 0);
        a = __builtin_amdgcn_mfma_f32_16x16x32_bf16(qf1, k1f, a, 0, 0, 0);
        sc[kt] = a;
    }

    float mx[4] = {-3e38f, -3e38f, -3e38f, -3e38f};
#pragma unroll
    for (int kt = 0; kt < 9; ++kt) {
        int jg = j0 + (wave + kt) * 16 + lm;
#pragma unroll
        for (int r = 0; r < 4; ++r) {
            int irow = q0 + wave * 16 + quad * 4 + r;
            int diff = irow - jg;
            bool ok = (jg >= 0) && (jg < 1024) && (diff <= 64) && (diff >= -64);
            float s = ok ? sc[kt][r] * 0.125f : -30000.0f;
            sc[kt][r] = s;
            mx[r] = fmaxf(mx[r], s);
        }
    }
#pragma unroll
    for (int off = 1; off <= 8; off <<= 1)
#pragma unroll
        for (int r = 0; r < 4; ++r)
            mx[r] = fmaxf(mx[r], __shfl_xor(mx[r], off, 64));

    float sum[4] = {0.f, 0.f, 0.f, 0.f};
#pragma unroll
    for (int kt = 0; kt < 9; ++kt)
#pragma unroll
        for (int r = 0; r < 4; ++r) {
            float p = __expf(sc[kt][r] - mx[r]);
            sc[kt][r] = p;
            sum[r] += p;
        }
#pragma unroll
    for (int off = 1; off <= 8; off <<= 1)
#pragma unroll
        for (int r = 0; r < 4; ++r)
            sum[r] += __shfl_xor(sum[r], off, 64);

    __syncthreads();  // done reading Ks as K tile
    unsigned short* Pb = Ks + wave * 3200;  // per-wave P [16][VP]
    // P-store: permute row order by quad -> quad-pair bank aliasing (4-way)
    // becomes <=2-way. Same data written, same layout.
#pragma unroll
    for (int kt = 0; kt < 9; ++kt) {
        int akt = wave + kt;
#pragma unroll
        for (int r0 = 0; r0 < 4; ++r0) {
            int r = (r0 + quad) & 3;
            Pb[(quad * 4 + r) * VP + akt * 16 + lm] = f2b(sc[kt][r]);
        }
    }
    {   // zero the one tile in this wave's PV range not covered by [w, w+8]
        int zkt = (wave & 1) ? (wave - 1) : (wave + 9);
#pragma unroll
        for (int r0 = 0; r0 < 4; ++r0) {
            int r = (r0 + quad) & 3;
            Pb[(quad * 4 + r) * VP + zkt * 16 + lm] = 0;
        }
    }
    __syncthreads();

    // O[16q][64d] = P * V^T over 5 of 6 32-key chunks
    int jclo = wave >> 1;
    f32x4 o[4];
#pragma unroll
    for (int n = 0; n < 4; ++n) o[n] = (f32x4){0.f, 0.f, 0.f, 0.f};
#pragma unroll
    for (int jc2 = 0; jc2 < 5; ++jc2) {
        int jc = jclo + jc2;
        bf16x8 pf = *(const bf16x8*)(Pb + lm * VP + jc * 32 + quad * 8);
#pragma unroll
        for (int n = 0; n < 4; ++n) {
            bf16x8 vf = *(const bf16x8*)(Vt + (n * 16 + lm) * VP + jc * 32 + quad * 8);
            o[n] = __builtin_amdgcn_mfma_f32_16x16x32_bf16(pf, vf, o[n], 0, 0, 0);
        }
    }

    float inv[4];
#pragma unroll
    for (int r = 0; r < 4; ++r) inv[r] = 1.0f / sum[r];
#pragma unroll
    for (int n = 0; n < 4; ++n)
#pragma unroll
        for (int r = 0; r < 4; ++r) {
            int orow = q0 + wave * 16 + quad * 4 + r;
            size_t oidx = ((size_t)(b * 1024 + orow)) * 1024 + h * 64 + n * 16 + lm;
            Og[oidx] = f2b(o[n][r] * inv[r]);
        }
}

// ---- proj GEMM: out[M,N] = attn[M,K] * w2b[N,K]^T + b2, f32 out ----
__global__ void __launch_bounds__(256) gemm_proj(
    const unsigned short* __restrict__ A,   // attn [8192,1024] bf16
    const unsigned short* __restrict__ W,   // w2b [1024,1024] bf16
    const float* __restrict__ bias,         // [1024] f32
    float* __restrict__ Out)                // [8192,1024] f32
{
    const int K = 1024;
    int n0 = blockIdx.x * BN;
    int m0 = blockIdx.y * BM;
    int tid = threadIdx.x;
    int wave = tid >> 6, lane = tid & 63;
    int lm = lane & 15, quad = lane >> 4;
    int mblk = (wave & 1) * 64, nblk = (wave >> 1) * 64;

    __shared__ unsigned short As[BM * BK];
    __shared__ unsigned short Bs[BN * BK];

    int drow = lane >> 3;
    int gcc  = (lane & 7) ^ drow;
    const unsigned short* ga[4]; const unsigned short* gb[4];
    unsigned short *la[4], *lb[4];
#pragma unroll
    for (int p = 0; p < 4; ++p) {
        int r = wave * 32 + p * 8 + drow;
        ga[p] = A + (size_t)(m0 + r) * K + gcc * 8;
        gb[p] = W + (size_t)(n0 + r) * K + gcc * 8;
        la[p] = As + (wave * 32 + p * 8) * 64;
        lb[p] = Bs + (wave * 32 + p * 8) * 64;
    }
    int lm7 = lm & 7;

    f32x4 acc[4][4];
#pragma unroll
    for (int i = 0; i < 4; ++i)
#pragma unroll
        for (int j = 0; j < 4; ++j)
            acc[i][j] = (f32x4){0.f, 0.f, 0.f, 0.f};

    for (int k0 = 0; k0 < K; k0 += BK) {
        __syncthreads();
#pragma unroll
        for (int p = 0; p < 4; ++p) gld16(ga[p] + k0, la[p]);
#pragma unroll
        for (int p = 0; p < 4; ++p) gld16(gb[p] + k0, lb[p]);
        __syncthreads();
        bf16x8 af[4][2], bfr[4][2];
#pragma unroll
        for (int i = 0; i < 4; ++i)
#pragma unroll
            for (int hhh = 0; hhh < 2; ++hhh)
                af[i][hhh] = *(const bf16x8*)(As + (mblk + i * 16 + lm) * 64 +
                                              (((hhh * 4 + quad) ^ lm7) << 3));
#pragma unroll
        for (int j = 0; j < 4; ++j)
#pragma unroll
            for (int hhh = 0; hhh < 2; ++hhh)
                bfr[j][hhh] = *(const bf16x8*)(Bs + (nblk + j * 16 + lm) * 64 +
                                               (((hhh * 4 + quad) ^ lm7) << 3));
#pragma unroll
        for (int i = 0; i < 4; ++i)
#pragma unroll
            for (int j = 0; j < 4; ++j) {
                acc[i][j] = __builtin_amdgcn_mfma_f32_16x16x32_bf16(af[i][0], bfr[j][0], acc[i][j], 0, 0, 0);
                acc[i][j] = __builtin_amdgcn_mfma_f32_16x16x32_bf16(af[i][1], bfr[j][1], acc[i][j], 0, 0, 0);
            }
    }

#pragma unroll
    for (int j = 0; j < 4; ++j) {
        int n = n0 + nblk + j * 16 + lm;
        float bv = bias[n];
#pragma unroll
        for (int i = 0; i < 4; ++i) {
#pragma unroll
            for (int r = 0; r < 4; ++r) {
                int m = m0 + mblk + i * 16 + quad * 4 + r;
                Out[(size_t)m * 1024 + n] = acc[i][j][r] + bv;
            }
        }
    }
}

extern "C" void kernel_launch(void* const* d_in, const int* in_sizes, int n_in,
                              void* d_out, int out_size, void* d_ws, size_t ws_size,
                              hipStream_t stream) {
    const float* x  = (const float*)d_in[0];  // [8,1024,1024] f32
    const float* w1 = (const float*)d_in[1];  // [3072,1024] f32
    const float* b1 = (const float*)d_in[2];  // [3072] f32
    const float* w2 = (const float*)d_in[3];  // [1024,1024] f32
    const float* b2 = (const float*)d_in[4];  // [1024] f32
    float* out = (float*)d_out;               // [8192,1024] f32

    // ws (56 MiB peak):
    //  [0,16Mi)   xb  -> overlaid by attn after gemm_qkv
    //  [16,22Mi)  w1b -> dead after gemm_qkv
    //  [22,24Mi)  w2b
    //  [24,40Mi)  q   [40,56Mi) k
    //  v lives in d_out's first 16 MiB (dead before gemm_proj writes out)
    char* ws = (char*)d_ws;
    const size_t MB = 1024 * 1024;
    unsigned short* xb   = (unsigned short*)(ws);
    unsigned short* w1b  = (unsigned short*)(ws + 16 * MB);
    unsigned short* w2b  = (unsigned short*)(ws + 22 * MB);
    unsigned short* q    = (unsigned short*)(ws + 24 * MB);
    unsigned short* k    = (unsigned short*)(ws + 40 * MB);
    unsigned short* v    = (unsigned short*)d_out;
    unsigned short* attn = (unsigned short*)(ws);

    dim3 blk(256);
    cast_inputs<<<1536, blk, 0, stream>>>(
        (const float4*)x, (const float4*)w1, (const float4*)w2,
        (uint4*)xb, (uint4*)w1b, (uint4*)w2b);
    gemm_qkv<<<dim3(24, 64), blk, 0, stream>>>(xb, w1b, b1, q, k, v);
    attn_local<<<dim3(2048), blk, 0, stream>>>(q, k, v, attn);
    gemm_proj<<<dim3(8, 64), blk, 0, stream>>>(attn, w2b, b2, out);
}